// Round 17
// baseline (167.225 us; speedup 1.0000x reference)
//
#include <hip/hip_runtime.h>
#include <hip/hip_bf16.h>

#define TPB 256

typedef float f32x4 __attribute__((ext_vector_type(4)));
typedef short s16x8 __attribute__((ext_vector_type(8)));

static constexpr int B_ = 32;
static constexpr int C_ = 128;
static constexpr int N_ = 1024;
static constexpr int K_ = 9;
static constexpr int CN_ = C_ * N_;
static constexpr float INFV = 1.0e10f;
static constexpr float EPS_ = 1e-8f;

// ws layout (float slots) — r14-proven 29 MB layout, byte-identical
static constexpr size_t XNT_OFF = 0;                             // xnt [B][N][C] fp32
static constexpr size_t XNB_OFF = (size_t)B_ * CN_;              // xnb [B][N][C] bf16 (xtb aliases later)
static constexpr size_t WBH_OFF = XNB_OFF + (size_t)B_ * CN_ / 2;
static constexpr size_t WBL_OFF = WBH_OFF + (size_t)K_ * C_ * C_ / 2;
static constexpr size_t CI_OFF  = WBL_OFF + (size_t)K_ * C_ * C_ / 2;  // [B][N][16] int
static constexpr size_t IDX_OFF = CI_OFF + (size_t)B_ * N_ * 16;       // [B][N][9] int

__device__ __forceinline__ void gload_lds16(const void* g, void* l) {
    __builtin_amdgcn_global_load_lds((const __attribute__((address_space(1))) void*)g,
                                     (__attribute__((address_space(3))) void*)l, 16, 0, 0);
}

__device__ __forceinline__ unsigned umin3(unsigned a, unsigned b, unsigned c) {
    return min(min(a, b), c);                  // expect v_min3_u32
}

// unsorted top-16 keyset insert: replace unique min slot, min3-structured tree
#define KINSERT16(KEYS, THR, KEXPR)                                         \
    {                                                                       \
        unsigned _k = (KEXPR);                                              \
        if (_k > (THR)) {                                                   \
            _Pragma("unroll")                                               \
            for (int _p = 0; _p < 16; ++_p)                                 \
                KEYS[_p] = (KEYS[_p] == (THR)) ? _k : KEYS[_p];             \
            unsigned _m0 = umin3(KEYS[0],  KEYS[1],  KEYS[2]);              \
            unsigned _m1 = umin3(KEYS[3],  KEYS[4],  KEYS[5]);              \
            unsigned _m2 = umin3(KEYS[6],  KEYS[7],  KEYS[8]);              \
            unsigned _m3 = umin3(KEYS[9],  KEYS[10], KEYS[11]);             \
            unsigned _m4 = umin3(KEYS[12], KEYS[13], KEYS[14]);             \
            (THR) = min(umin3(_m0, _m1, _m2), umin3(_m3, _m4, KEYS[15]));   \
        }                                                                   \
    }

// monotone (value, smaller-index-wins) packed key; drops 10 low mantissa bits
__device__ __forceinline__ unsigned simkey(float v, unsigned lowfield) {
    unsigned u = __float_as_uint(v);
    u ^= ((unsigned)((int)u >> 31) | 0x80000000u);
    return (u & 0xFFFFFC00u) | lowfield;
}

// ---------------------------------------------------------------------------
// 1) normtrans: xnt[b][n][c] = x[b][c][n]/(||x[:,n]||+eps) fp32; xnb = bf16(same)
// ---------------------------------------------------------------------------
__global__ __launch_bounds__(TPB) void normtrans_kernel(const float* __restrict__ x,
                                                        float* __restrict__ xnt,
                                                        __hip_bfloat16* __restrict__ xnb) {
    __shared__ float lds[128][65];
    __shared__ float nrm[64];
    int b = blockIdx.x >> 4, n0 = (blockIdx.x & 15) << 6;
    const float* src = x + (size_t)b * CN_ + n0;
    #pragma unroll 4
    for (int i = 0; i < 32; ++i) {
        int flat = i * TPB + threadIdx.x;
        int c = flat >> 6, nn = flat & 63;
        lds[c][nn] = src[(size_t)c * N_ + nn];
    }
    __syncthreads();
    if (threadIdx.x < 64) {
        float ss = 0.f;
        #pragma unroll 8
        for (int c = 0; c < C_; ++c) { float v = lds[c][threadIdx.x]; ss += v * v; }
        nrm[threadIdx.x] = sqrtf(ss) + EPS_;
    }
    __syncthreads();
    float* dstf = xnt + ((size_t)b * N_ + n0) * C_;
    __hip_bfloat16* dstb = xnb + ((size_t)b * N_ + n0) * C_;
    #pragma unroll 4
    for (int i = 0; i < 32; ++i) {
        int flat = i * TPB + threadIdx.x;
        int nn = flat >> 7, c = flat & 127;
        float v = lds[c][nn] / nrm[nn];
        dstf[(size_t)nn * C_ + c] = v;
        dstb[(size_t)nn * C_ + c] = __float2bfloat16(v);
    }
}

// ---------------------------------------------------------------------------
// 2) xtb[b][n][c] = bf16(x[b][c][n])   (raw features for conv gather)
// ---------------------------------------------------------------------------
__global__ __launch_bounds__(TPB) void transpose_bf16_kernel(const float* __restrict__ x,
                                                             __hip_bfloat16* __restrict__ xtb) {
    __shared__ float lds[128][65];
    int b = blockIdx.x >> 4, n0 = (blockIdx.x & 15) << 6;
    const float* src = x + (size_t)b * CN_ + n0;
    #pragma unroll 4
    for (int i = 0; i < 32; ++i) {
        int flat = i * TPB + threadIdx.x;
        int c = flat >> 6, nn = flat & 63;
        lds[c][nn] = src[(size_t)c * N_ + nn];
    }
    __syncthreads();
    __hip_bfloat16* dst = xtb + (size_t)b * CN_ + (size_t)n0 * C_;
    #pragma unroll 4
    for (int i = 0; i < 32; ++i) {
        int flat = i * TPB + threadIdx.x;
        int nn = flat >> 7, c = flat & 127;
        dst[(size_t)nn * C_ + c] = __float2bfloat16(lds[c][nn]);
    }
}

// ---------------------------------------------------------------------------
// 3) split-bf16 weights: wh/wl [k][o][c]
// ---------------------------------------------------------------------------
__global__ __launch_bounds__(TPB) void wbprep_kernel(const float* __restrict__ W,
                                                     __hip_bfloat16* __restrict__ wh,
                                                     __hip_bfloat16* __restrict__ wl) {
    int t = blockIdx.x * TPB + threadIdx.x;
    int k = t / (C_ * C_);
    int r = t - k * (C_ * C_);
    int o = r >> 7, c = r & 127;
    float w = W[((size_t)o * C_ + c) * K_ + k];
    __hip_bfloat16 h = __float2bfloat16(w);
    wh[t] = h;
    wl[t] = __float2bfloat16(w - __bfloat162float(h));
}

// ---------------------------------------------------------------------------
// 4) phase-1 (UNCHANGED from passing r14): swapped-operand MFMA sim,
//    register-direct top-16 keyset scan. 32-row tiles, 4 waves, 4 blocks/CU.
// ---------------------------------------------------------------------------
__global__ __launch_bounds__(TPB, 4) void sim_mfma_topk_kernel(const __hip_bfloat16* __restrict__ xnb,
                                                               int* __restrict__ ci) {
    __shared__ __align__(16) ushort SH[4096 + 16384];   // Ab [2][32*64] | Bb [2][128*64]
    ushort* Ab = SH;                                    // mbuf (u32) aliases Ab at merge
    ushort* Bb = SH + 4096;

    const int tid = threadIdx.x;
    const int lane = tid & 63;
    const int wv = tid >> 6;                  // 0..3
    const int rb = wv & 1;                    // 16-row block within the 32-row tile
    const int ch = wv >> 1;                   // col half (64 cols of each 128-tile)
    const int b  = blockIdx.x >> 5;
    const int n0 = (blockIdx.x & 31) << 5;    // 32 rows per block
    const __hip_bfloat16* xb = xnb + (size_t)b * CN_;
    const int l15 = lane & 15, l7 = lane & 7, lq = lane >> 4;
    const int swz = ((lane & 7) ^ (lane >> 3)) * 8;
    const int grow = n0 + 16 * rb + l15;      // the row this lane selects for

    // stage Ab (32 rows x 128c, 2 halves): 8 gll units, 2 per wave
    #pragma unroll
    for (int q = 0; q < 2; ++q) {
        int u = 2 * wv + q;
        int hh = u >> 2, r0 = (u & 3) * 8;
        gload_lds16(xb + (size_t)(n0 + r0 + (lane >> 3)) * C_ + hh * 64 + swz,
                    Ab + hh * 2048 + r0 * 64);
    }
    // stage Bb tile 0 (tokens 0..127): 32 units, 8 per wave
    #pragma unroll
    for (int q = 0; q < 8; ++q) {
        int u = 8 * wv + q;
        int hh = u >> 4, r0 = (u & 15) * 8;
        gload_lds16(xb + (size_t)(r0 + (lane >> 3)) * C_ + hh * 64 + swz,
                    Bb + hh * 8192 + r0 * 64);
    }
    __syncthreads();

    // row fragments (B-operand of the swapped MFMA), constant across all mt
    s16x8 af[2][2];
    #pragma unroll
    for (int h = 0; h < 2; ++h)
        #pragma unroll
        for (int kc = 0; kc < 2; ++kc)
            af[h][kc] = *(const s16x8*)&Ab[h * 2048 + (16 * rb + l15) * 64 + (((kc * 4 + lq) ^ l7) << 3)];

    unsigned keys[16];
    #pragma unroll
    for (int p = 0; p < 16; ++p) keys[p] = (unsigned)p;   // distinct, below any real key
    unsigned thr = 0u;

    #pragma unroll 1
    for (int mt = 0; mt < 8; ++mt) {
        f32x4 acc[4];
        #pragma unroll
        for (int t = 0; t < 4; ++t) acc[t] = (f32x4){0.f, 0.f, 0.f, 0.f};

        #pragma unroll
        for (int h = 0; h < 2; ++h)
            #pragma unroll
            for (int kc = 0; kc < 2; ++kc) {
                const int phys = ((kc * 4 + lq) ^ l7) << 3;
                #pragma unroll
                for (int t = 0; t < 4; ++t) {
                    s16x8 bb = *(const s16x8*)&Bb[h * 8192 + (64 * ch + 16 * t + l15) * 64 + phys];
                    // SWAPPED operands: A = col fragment, B = row fragment
                    acc[t] = __builtin_amdgcn_mfma_f32_16x16x32_bf16(bb, af[h][kc], acc[t], 0, 0, 0);
                }
            }
        __syncthreads();                      // all MFMA reads of Bb done

        if (mt < 7) {                         // stage next 128 tokens
            #pragma unroll
            for (int q = 0; q < 8; ++q) {
                int u = 8 * wv + q;
                int hh = u >> 4, r0 = (u & 15) * 8;
                gload_lds16(xb + (size_t)(128 * (mt + 1) + r0 + (lane >> 3)) * C_ + hh * 64 + swz,
                            Bb + hh * 8192 + r0 * 64);
            }
        }

        // register-direct scan: lane owns row grow; cols = mt*128+64ch+4lq+16t+r
        const int colb = (mt << 7) + 64 * ch + 4 * lq;
        #pragma unroll
        for (int t = 0; t < 4; ++t)
            #pragma unroll
            for (int r = 0; r < 4; ++r) {
                int gcol = colb + 16 * t + r;
                float v = acc[t][r];
                if (gcol == grow) v = INFV;   // self always a candidate
                KINSERT16(keys, thr, simkey(v, 1023u - (unsigned)gcol))
            }
        __syncthreads();                      // drains gll: next Bb ready
    }

    // merge the 4 lq lanes (snapshot BEFORE insert: in-place shfl merge is a
    // read-during-mutation hazard; partner col-sets are disjoint at both steps)
    #pragma unroll
    for (int d = 16; d <= 32; d <<= 1) {
        unsigned inc[16];
        #pragma unroll
        for (int p = 0; p < 16; ++p)
            inc[p] = (unsigned)__shfl_xor((int)keys[p], d);
        #pragma unroll
        for (int p = 0; p < 16; ++p) KINSERT16(keys, thr, inc[p])
    }

    // cross-wave merge (col half 1 -> half 0) via small LDS buffer over Ab
    unsigned* mbuf = (unsigned*)SH;           // [32 rows][16 keys]
    if (ch == 1 && lq == 0) {
        #pragma unroll
        for (int p = 0; p < 16; ++p) mbuf[(16 * rb + l15) * 16 + p] = keys[p];
    }
    __syncthreads();
    if (ch == 0 && lq == 0) {
        #pragma unroll
        for (int p = 0; p < 16; ++p) KINSERT16(keys, thr, mbuf[(16 * rb + l15) * 16 + p])
        int* op = ci + ((size_t)b * N_ + grow) * 16;
        #pragma unroll
        for (int p = 0; p < 16; ++p) op[p] = 1023 - (int)(keys[p] & 1023u);
    }
}

// ---------------------------------------------------------------------------
// 5) rescore (rank-based, BITWISE-r14 values): one lane = one candidate.
//    Dot computed as 16 partials (sequential fma over c = l+16t — exactly
//    r14's per-lane chain) combined in the exact binary-tree association of
//    r14's butterfly reduce -> v is byte-identical to r14's. Comparator
//    identical to INSERT9's -> idx output byte-identical to passing r14.
// ---------------------------------------------------------------------------
__global__ __launch_bounds__(TPB) void rescore_kernel(const float* __restrict__ xnt,
                                                      const int* __restrict__ ci,
                                                      int* __restrict__ idxo) {
    const int tid = threadIdx.x;
    const int g = tid >> 4, l = tid & 15;
    const size_t row = (size_t)blockIdx.x * 16 + g;       // global row 0..32767
    const int nrow = (int)(row & (N_ - 1));               // token index within batch
    const float* xbase = xnt + (row >> 10) * (size_t)CN_; // batch base

    const int cand = ci[row * 16 + l];
    const float4* a4 = (const float4*)(xbase + (size_t)nrow * C_);  // broadcast in group
    const float4* b4 = (const float4*)(xbase + (size_t)cand * C_);

    // 16 partials: partial lp accumulates c = lp + 16t, t ascending (r14 chain)
    float p[16];
    #pragma unroll
    for (int i = 0; i < 16; ++i) p[i] = 0.f;
    #pragma unroll
    for (int q = 0; q < 32; ++q) {            // float4 q covers c = 4q..4q+3
        float4 av = a4[q], bv = b4[q];
        const int base = (q & 3) << 2;        // static after unroll
        p[base + 0] = fmaf(av.x, bv.x, p[base + 0]);
        p[base + 1] = fmaf(av.y, bv.y, p[base + 1]);
        p[base + 2] = fmaf(av.z, bv.z, p[base + 2]);
        p[base + 3] = fmaf(av.w, bv.w, p[base + 3]);
    }
    // exact binary-tree association of r14's shfl_xor d=1,2,4,8 reduce
    float s1_0 = p[0] + p[1],   s1_1 = p[2] + p[3];
    float s1_2 = p[4] + p[5],   s1_3 = p[6] + p[7];
    float s1_4 = p[8] + p[9],   s1_5 = p[10] + p[11];
    float s1_6 = p[12] + p[13], s1_7 = p[14] + p[15];
    float s2_0 = s1_0 + s1_1, s2_1 = s1_2 + s1_3;
    float s2_2 = s1_4 + s1_5, s2_3 = s1_6 + s1_7;
    float s3_0 = s2_0 + s2_1, s3_1 = s2_2 + s2_3;
    float v = (cand == nrow) ? INFV : (s3_0 + s3_1);

    // stable rank among the 16 lanes of this group (same comparator as INSERT9)
    int rank = 0;
    #pragma unroll
    for (int j = 1; j < 16; ++j) {
        float vv = __shfl_xor(v, j, 16);
        int   cc = __shfl_xor(cand, j, 16);
        rank += ((vv > v) || (vv == v && cc < cand)) ? 1 : 0;
    }
    if (rank < 9) idxo[row * 9 + rank] = cand;
}

// ---------------------------------------------------------------------------
// 6) MFMA conv (unchanged, passing): 128o x 128n per block
// ---------------------------------------------------------------------------
__global__ __launch_bounds__(TPB) void conv_mfma_kernel(const __hip_bfloat16* __restrict__ xtb,
                                                        const __hip_bfloat16* __restrict__ wbh,
                                                        const __hip_bfloat16* __restrict__ wbl,
                                                        const int* __restrict__ idxi,
                                                        float* __restrict__ out) {
    __shared__ __align__(16) __hip_bfloat16 gbuf[2][128 * 64];
    __shared__ __align__(16) __hip_bfloat16 hbuf[2][128 * 64];
    __shared__ __align__(16) __hip_bfloat16 lbuf[2][128 * 64];
    __shared__ int ids[K_ * 128];

    const int tid = threadIdx.x;
    const int lane = tid & 63;
    const int wv = tid >> 6;
    const int b  = blockIdx.x >> 3;
    const int n0 = (blockIdx.x & 7) << 7;
    const __hip_bfloat16* xb = xtb + (size_t)b * CN_;

    for (int j = tid; j < K_ * 128; j += TPB) {
        int k = j >> 7, r = j & 127;
        ids[j] = idxi[((size_t)b * N_ + n0 + r) * K_ + k];
    }
    __syncthreads();

    f32x4 acc[2][8];
    #pragma unroll
    for (int mt = 0; mt < 2; ++mt)
        #pragma unroll
        for (int nt = 0; nt < 8; ++nt) acc[mt][nt] = (f32x4){0.f, 0.f, 0.f, 0.f};

    const int swz = ((lane & 7) ^ (lane >> 3)) * 8;

#define CONV_STAGE(S, PB)                                                               \
    {                                                                                   \
        const int k_ = (S) >> 1, ch_ = ((S) & 1) * 64;                                  \
        _Pragma("unroll")                                                               \
        for (int q_ = 0; q_ < 4; ++q_) {                                                \
            int row_ = 32 * wv + 8 * q_ + (lane >> 3);                                  \
            int tok_ = ids[k_ * 128 + row_];                                            \
            gload_lds16(xb + (size_t)tok_ * C_ + ch_ + swz, &gbuf[PB][(32 * wv + 8 * q_) * 64]); \
            const size_t wr_ = ((size_t)k_ * 128 + row_) * C_ + ch_ + swz;              \
            gload_lds16(wbh + wr_, &hbuf[PB][(32 * wv + 8 * q_) * 64]);                 \
            gload_lds16(wbl + wr_, &lbuf[PB][(32 * wv + 8 * q_) * 64]);                 \
        }                                                                               \
    }

    CONV_STAGE(0, 0)
    __syncthreads();

    const int l15 = lane & 15, l7 = lane & 7, lq = lane >> 4;
    int pb = 0;
    #pragma unroll 1
    for (int s = 0; s < 18; ++s) {
        if (s < 17) CONV_STAGE(s + 1, pb ^ 1)
        const __hip_bfloat16* G = gbuf[pb];
        const __hip_bfloat16* H = hbuf[pb];
        const __hip_bfloat16* L = lbuf[pb];
        #pragma unroll
        for (int kc = 0; kc < 2; ++kc) {
            const int phys = ((kc * 4 + lq) ^ l7) * 8;
            s16x8 bb[8];
            #pragma unroll
            for (int nt = 0; nt < 8; ++nt)
                bb[nt] = *(const s16x8*)&G[(16 * nt + l15) * 64 + phys];
            #pragma unroll
            for (int mt = 0; mt < 2; ++mt) {
                const int orow = (32 * wv + 16 * mt + l15) * 64 + phys;
                s16x8 ah = *(const s16x8*)&H[orow];
                s16x8 al = *(const s16x8*)&L[orow];
                #pragma unroll
                for (int nt = 0; nt < 8; ++nt) {
                    acc[mt][nt] = __builtin_amdgcn_mfma_f32_16x16x32_bf16(ah, bb[nt], acc[mt][nt], 0, 0, 0);
                    acc[mt][nt] = __builtin_amdgcn_mfma_f32_16x16x32_bf16(al, bb[nt], acc[mt][nt], 0, 0, 0);
                }
            }
        }
        __syncthreads();
        pb ^= 1;
    }

    float* ob = out + (size_t)b * CN_;
    #pragma unroll
    for (int mt = 0; mt < 2; ++mt)
        #pragma unroll
        for (int nt = 0; nt < 8; ++nt) {
            int o = 32 * wv + 16 * mt + lq * 4;
            int n = n0 + 16 * nt + l15;
            #pragma unroll
            for (int r = 0; r < 4; ++r)
                ob[(size_t)(o + r) * N_ + n] = acc[mt][nt][r];
        }
#undef CONV_STAGE
}

// ---------------------------------------------------------------------------
extern "C" void kernel_launch(void* const* d_in, const int* in_sizes, int n_in,
                              void* d_out, int out_size, void* d_ws, size_t ws_size,
                              hipStream_t stream) {
    (void)in_sizes; (void)n_in; (void)out_size; (void)ws_size;
    const float* x = (const float*)d_in[0];
    const float* W = (const float*)d_in[1];
    float* out = (float*)d_out;
    float* ws  = (float*)d_ws;

    float* xnt = ws + XNT_OFF;
    __hip_bfloat16* xnb = (__hip_bfloat16*)(ws + XNB_OFF);
    __hip_bfloat16* xtb = (__hip_bfloat16*)(ws + XNB_OFF);  // aliases xnb (disjoint lifetime)
    __hip_bfloat16* wbh = (__hip_bfloat16*)(ws + WBH_OFF);
    __hip_bfloat16* wbl = (__hip_bfloat16*)(ws + WBL_OFF);
    int* ci  = (int*)(ws + CI_OFF);
    int* idx = (int*)(ws + IDX_OFF);

    normtrans_kernel<<<B_ * 16, TPB, 0, stream>>>(x, xnt, xnb);
    wbprep_kernel<<<(K_ * C_ * C_) / TPB, TPB, 0, stream>>>(W, wbh, wbl);
    sim_mfma_topk_kernel<<<B_ * 32, TPB, 0, stream>>>(xnb, ci);
    rescore_kernel<<<(B_ * N_) / 16, TPB, 0, stream>>>(xnt, ci, idx);
    transpose_bf16_kernel<<<B_ * 16, TPB, 0, stream>>>(x, xtb);  // xnb dead now
    conv_mfma_kernel<<<B_ * 8, TPB, 0, stream>>>(xtb, wbh, wbl, idx, out);
}

// Round 18
// 149.008 us; speedup vs baseline: 1.1223x; 1.1223x over previous
//
#include <hip/hip_runtime.h>
#include <hip/hip_bf16.h>

#define TPB 256

typedef float f32x4 __attribute__((ext_vector_type(4)));
typedef short s16x8 __attribute__((ext_vector_type(8)));

static constexpr int B_ = 32;
static constexpr int C_ = 128;
static constexpr int N_ = 1024;
static constexpr int K_ = 9;
static constexpr int CN_ = C_ * N_;
static constexpr float INFV = 1.0e10f;
static constexpr float EPS_ = 1e-8f;

// ---- common offsets (float slots) ----
static constexpr size_t XNT_OFF = 0;                              // xnt [B][N][C] fp32
static constexpr size_t XNB_OFF = (size_t)B_ * CN_;               // xnb [B][N][C] bf16

// ---- fallback layout (r14-proven, 29 MB; xtb aliases xnb) ----
static constexpr size_t WBH_F = XNB_OFF + (size_t)B_ * CN_ / 2;
static constexpr size_t WBL_F = WBH_F + (size_t)K_ * C_ * C_ / 2;
static constexpr size_t CI_F  = WBL_F + (size_t)K_ * C_ * C_ / 2;      // [B][N][16] int
static constexpr size_t IDX_F = CI_F + (size_t)B_ * N_ * 16;           // [B][N][9] int

// ---- fused layout (37.4 MB; xtb separate) ----
static constexpr size_t XTB_U = XNB_OFF + (size_t)B_ * CN_ / 2;        // xtb [B][N][C] bf16
static constexpr size_t WBH_U = XTB_U + (size_t)B_ * CN_ / 2;
static constexpr size_t WBL_U = WBH_U + (size_t)K_ * C_ * C_ / 2;
static constexpr size_t CI_U  = WBL_U + (size_t)K_ * C_ * C_ / 2;
static constexpr size_t IDX_U = CI_U + (size_t)B_ * N_ * 16;
static constexpr size_t FUSED_END = IDX_U + (size_t)B_ * N_ * 9;       // 9,355,264 floats
static constexpr size_t FUSED_BYTES = FUSED_END * 4;                   // 37,421,056 B

__device__ __forceinline__ void gload_lds16(const void* g, void* l) {
    __builtin_amdgcn_global_load_lds((const __attribute__((address_space(1))) void*)g,
                                     (__attribute__((address_space(3))) void*)l, 16, 0, 0);
}

// exact stable top-9 insert (rescore)
#define INSERT9(Vv, Ii, vexpr, gmexpr)                                      \
    {                                                                       \
        float _v = (vexpr); int _gm = (gmexpr);                             \
        bool bp[9];                                                         \
        _Pragma("unroll")                                                   \
        for (int _p = 0; _p < 9; ++_p)                                      \
            bp[_p] = (_v > Vv[_p]) || (_v == Vv[_p] && _gm < Ii[_p]);       \
        if (bp[8]) {                                                        \
            _Pragma("unroll")                                               \
            for (int _p = 8; _p >= 1; --_p) {                               \
                Vv[_p] = bp[_p - 1] ? Vv[_p - 1] : (bp[_p] ? _v  : Vv[_p]); \
                Ii[_p] = bp[_p - 1] ? Ii[_p - 1] : (bp[_p] ? _gm : Ii[_p]); \
            }                                                               \
            if (bp[0]) { Vv[0] = _v; Ii[0] = _gm; }                         \
        }                                                                   \
    }

__device__ __forceinline__ unsigned umin3(unsigned a, unsigned b, unsigned c) {
    return min(min(a, b), c);                  // expect v_min3_u32
}

// unsorted top-16 keyset insert: replace unique min slot, min3-structured tree
#define KINSERT16(KEYS, THR, KEXPR)                                         \
    {                                                                       \
        unsigned _k = (KEXPR);                                              \
        if (_k > (THR)) {                                                   \
            _Pragma("unroll")                                               \
            for (int _p = 0; _p < 16; ++_p)                                 \
                KEYS[_p] = (KEYS[_p] == (THR)) ? _k : KEYS[_p];             \
            unsigned _m0 = umin3(KEYS[0],  KEYS[1],  KEYS[2]);              \
            unsigned _m1 = umin3(KEYS[3],  KEYS[4],  KEYS[5]);              \
            unsigned _m2 = umin3(KEYS[6],  KEYS[7],  KEYS[8]);              \
            unsigned _m3 = umin3(KEYS[9],  KEYS[10], KEYS[11]);             \
            unsigned _m4 = umin3(KEYS[12], KEYS[13], KEYS[14]);             \
            (THR) = min(umin3(_m0, _m1, _m2), umin3(_m3, _m4, KEYS[15]));   \
        }                                                                   \
    }

// monotone (value, smaller-index-wins) packed key; drops 10 low mantissa bits
__device__ __forceinline__ unsigned simkey(float v, unsigned lowfield) {
    unsigned u = __float_as_uint(v);
    u ^= ((unsigned)((int)u >> 31) | 0x80000000u);
    return (u & 0xFFFFFC00u) | lowfield;
}

// ---------------------------------------------------------------------------
// 1a) FUSED prep: blocks [0,512) -> one read of x produces xnt/xnb/xtb
//     (write values index-identical to normtrans+transpose, exonerated r16/17);
//     blocks [512,1088) -> split-bf16 weights (wbprep body).
// ---------------------------------------------------------------------------
__global__ __launch_bounds__(TPB) void prep_all_kernel(const float* __restrict__ x,
                                                       const float* __restrict__ W,
                                                       float* __restrict__ xnt,
                                                       __hip_bfloat16* __restrict__ xnb,
                                                       __hip_bfloat16* __restrict__ xtb,
                                                       __hip_bfloat16* __restrict__ wh,
                                                       __hip_bfloat16* __restrict__ wl) {
    if (blockIdx.x >= 512) {                   // weight-split blocks (uniform branch)
        int t = (blockIdx.x - 512) * TPB + threadIdx.x;
        int k = t / (C_ * C_);
        int r = t - k * (C_ * C_);
        int o = r >> 7, c = r & 127;
        float w = W[((size_t)o * C_ + c) * K_ + k];
        __hip_bfloat16 h = __float2bfloat16(w);
        wh[t] = h;
        wl[t] = __float2bfloat16(w - __bfloat162float(h));
        return;
    }
    __shared__ float lds[128][65];
    __shared__ float nrm[64];
    int b = blockIdx.x >> 4, n0 = (blockIdx.x & 15) << 6;
    const float* src = x + (size_t)b * CN_ + n0;
    #pragma unroll 4
    for (int i = 0; i < 32; ++i) {
        int flat = i * TPB + threadIdx.x;
        int c = flat >> 6, nn = flat & 63;
        lds[c][nn] = src[(size_t)c * N_ + nn];
    }
    __syncthreads();
    if (threadIdx.x < 64) {
        float ss = 0.f;
        #pragma unroll 8
        for (int c = 0; c < C_; ++c) { float v = lds[c][threadIdx.x]; ss += v * v; }
        nrm[threadIdx.x] = sqrtf(ss) + EPS_;
    }
    __syncthreads();
    float* dstf = xnt + ((size_t)b * N_ + n0) * C_;
    __hip_bfloat16* dstb = xnb + ((size_t)b * N_ + n0) * C_;
    __hip_bfloat16* dstr = xtb + ((size_t)b * N_ + n0) * C_;
    #pragma unroll 4
    for (int i = 0; i < 32; ++i) {
        int flat = i * TPB + threadIdx.x;
        int nn = flat >> 7, c = flat & 127;
        float raw = lds[c][nn];
        float v = raw / nrm[nn];
        dstf[(size_t)nn * C_ + c] = v;
        dstb[(size_t)nn * C_ + c] = __float2bfloat16(v);
        dstr[(size_t)nn * C_ + c] = __float2bfloat16(raw);
    }
}

// ---------------------------------------------------------------------------
// 1b) fallback prep kernels — byte-identical to passing r14
// ---------------------------------------------------------------------------
__global__ __launch_bounds__(TPB) void normtrans_kernel(const float* __restrict__ x,
                                                        float* __restrict__ xnt,
                                                        __hip_bfloat16* __restrict__ xnb) {
    __shared__ float lds[128][65];
    __shared__ float nrm[64];
    int b = blockIdx.x >> 4, n0 = (blockIdx.x & 15) << 6;
    const float* src = x + (size_t)b * CN_ + n0;
    #pragma unroll 4
    for (int i = 0; i < 32; ++i) {
        int flat = i * TPB + threadIdx.x;
        int c = flat >> 6, nn = flat & 63;
        lds[c][nn] = src[(size_t)c * N_ + nn];
    }
    __syncthreads();
    if (threadIdx.x < 64) {
        float ss = 0.f;
        #pragma unroll 8
        for (int c = 0; c < C_; ++c) { float v = lds[c][threadIdx.x]; ss += v * v; }
        nrm[threadIdx.x] = sqrtf(ss) + EPS_;
    }
    __syncthreads();
    float* dstf = xnt + ((size_t)b * N_ + n0) * C_;
    __hip_bfloat16* dstb = xnb + ((size_t)b * N_ + n0) * C_;
    #pragma unroll 4
    for (int i = 0; i < 32; ++i) {
        int flat = i * TPB + threadIdx.x;
        int nn = flat >> 7, c = flat & 127;
        float v = lds[c][nn] / nrm[nn];
        dstf[(size_t)nn * C_ + c] = v;
        dstb[(size_t)nn * C_ + c] = __float2bfloat16(v);
    }
}

__global__ __launch_bounds__(TPB) void transpose_bf16_kernel(const float* __restrict__ x,
                                                             __hip_bfloat16* __restrict__ xtb) {
    __shared__ float lds[128][65];
    int b = blockIdx.x >> 4, n0 = (blockIdx.x & 15) << 6;
    const float* src = x + (size_t)b * CN_ + n0;
    #pragma unroll 4
    for (int i = 0; i < 32; ++i) {
        int flat = i * TPB + threadIdx.x;
        int c = flat >> 6, nn = flat & 63;
        lds[c][nn] = src[(size_t)c * N_ + nn];
    }
    __syncthreads();
    __hip_bfloat16* dst = xtb + (size_t)b * CN_ + (size_t)n0 * C_;
    #pragma unroll 4
    for (int i = 0; i < 32; ++i) {
        int flat = i * TPB + threadIdx.x;
        int nn = flat >> 7, c = flat & 127;
        dst[(size_t)nn * C_ + c] = __float2bfloat16(lds[c][nn]);
    }
}

__global__ __launch_bounds__(TPB) void wbprep_kernel(const float* __restrict__ W,
                                                     __hip_bfloat16* __restrict__ wh,
                                                     __hip_bfloat16* __restrict__ wl) {
    int t = blockIdx.x * TPB + threadIdx.x;
    int k = t / (C_ * C_);
    int r = t - k * (C_ * C_);
    int o = r >> 7, c = r & 127;
    float w = W[((size_t)o * C_ + c) * K_ + k];
    __hip_bfloat16 h = __float2bfloat16(w);
    wh[t] = h;
    wl[t] = __float2bfloat16(w - __bfloat162float(h));
}

// ---------------------------------------------------------------------------
// 2) phase-1 (UNCHANGED from passing r14): swapped-operand MFMA sim,
//    register-direct top-16 keyset scan. 32-row tiles, 4 waves, 4 blocks/CU.
// ---------------------------------------------------------------------------
__global__ __launch_bounds__(TPB, 4) void sim_mfma_topk_kernel(const __hip_bfloat16* __restrict__ xnb,
                                                               int* __restrict__ ci) {
    __shared__ __align__(16) ushort SH[4096 + 16384];   // Ab [2][32*64] | Bb [2][128*64]
    ushort* Ab = SH;                                    // mbuf (u32) aliases Ab at merge
    ushort* Bb = SH + 4096;

    const int tid = threadIdx.x;
    const int lane = tid & 63;
    const int wv = tid >> 6;                  // 0..3
    const int rb = wv & 1;                    // 16-row block within the 32-row tile
    const int ch = wv >> 1;                   // col half (64 cols of each 128-tile)
    const int b  = blockIdx.x >> 5;
    const int n0 = (blockIdx.x & 31) << 5;    // 32 rows per block
    const __hip_bfloat16* xb = xnb + (size_t)b * CN_;
    const int l15 = lane & 15, l7 = lane & 7, lq = lane >> 4;
    const int swz = ((lane & 7) ^ (lane >> 3)) * 8;
    const int grow = n0 + 16 * rb + l15;      // the row this lane selects for

    // stage Ab (32 rows x 128c, 2 halves): 8 gll units, 2 per wave
    #pragma unroll
    for (int q = 0; q < 2; ++q) {
        int u = 2 * wv + q;
        int hh = u >> 2, r0 = (u & 3) * 8;
        gload_lds16(xb + (size_t)(n0 + r0 + (lane >> 3)) * C_ + hh * 64 + swz,
                    Ab + hh * 2048 + r0 * 64);
    }
    // stage Bb tile 0 (tokens 0..127): 32 units, 8 per wave
    #pragma unroll
    for (int q = 0; q < 8; ++q) {
        int u = 8 * wv + q;
        int hh = u >> 4, r0 = (u & 15) * 8;
        gload_lds16(xb + (size_t)(r0 + (lane >> 3)) * C_ + hh * 64 + swz,
                    Bb + hh * 8192 + r0 * 64);
    }
    __syncthreads();

    // row fragments (B-operand of the swapped MFMA), constant across all mt
    s16x8 af[2][2];
    #pragma unroll
    for (int h = 0; h < 2; ++h)
        #pragma unroll
        for (int kc = 0; kc < 2; ++kc)
            af[h][kc] = *(const s16x8*)&Ab[h * 2048 + (16 * rb + l15) * 64 + (((kc * 4 + lq) ^ l7) << 3)];

    unsigned keys[16];
    #pragma unroll
    for (int p = 0; p < 16; ++p) keys[p] = (unsigned)p;   // distinct, below any real key
    unsigned thr = 0u;

    #pragma unroll 1
    for (int mt = 0; mt < 8; ++mt) {
        f32x4 acc[4];
        #pragma unroll
        for (int t = 0; t < 4; ++t) acc[t] = (f32x4){0.f, 0.f, 0.f, 0.f};

        #pragma unroll
        for (int h = 0; h < 2; ++h)
            #pragma unroll
            for (int kc = 0; kc < 2; ++kc) {
                const int phys = ((kc * 4 + lq) ^ l7) << 3;
                #pragma unroll
                for (int t = 0; t < 4; ++t) {
                    s16x8 bb = *(const s16x8*)&Bb[h * 8192 + (64 * ch + 16 * t + l15) * 64 + phys];
                    // SWAPPED operands: A = col fragment, B = row fragment
                    acc[t] = __builtin_amdgcn_mfma_f32_16x16x32_bf16(bb, af[h][kc], acc[t], 0, 0, 0);
                }
            }
        __syncthreads();                      // all MFMA reads of Bb done

        if (mt < 7) {                         // stage next 128 tokens
            #pragma unroll
            for (int q = 0; q < 8; ++q) {
                int u = 8 * wv + q;
                int hh = u >> 4, r0 = (u & 15) * 8;
                gload_lds16(xb + (size_t)(128 * (mt + 1) + r0 + (lane >> 3)) * C_ + hh * 64 + swz,
                            Bb + hh * 8192 + r0 * 64);
            }
        }

        // register-direct scan: lane owns row grow; cols = mt*128+64ch+4lq+16t+r
        const int colb = (mt << 7) + 64 * ch + 4 * lq;
        #pragma unroll
        for (int t = 0; t < 4; ++t)
            #pragma unroll
            for (int r = 0; r < 4; ++r) {
                int gcol = colb + 16 * t + r;
                float v = acc[t][r];
                if (gcol == grow) v = INFV;   // self always a candidate
                KINSERT16(keys, thr, simkey(v, 1023u - (unsigned)gcol))
            }
        __syncthreads();                      // drains gll: next Bb ready
    }

    // merge the 4 lq lanes (snapshot BEFORE insert: in-place shfl merge is a
    // read-during-mutation hazard; partner col-sets are disjoint at both steps)
    #pragma unroll
    for (int d = 16; d <= 32; d <<= 1) {
        unsigned inc[16];
        #pragma unroll
        for (int p = 0; p < 16; ++p)
            inc[p] = (unsigned)__shfl_xor((int)keys[p], d);
        #pragma unroll
        for (int p = 0; p < 16; ++p) KINSERT16(keys, thr, inc[p])
    }

    // cross-wave merge (col half 1 -> half 0) via small LDS buffer over Ab
    unsigned* mbuf = (unsigned*)SH;           // [32 rows][16 keys]
    if (ch == 1 && lq == 0) {
        #pragma unroll
        for (int p = 0; p < 16; ++p) mbuf[(16 * rb + l15) * 16 + p] = keys[p];
    }
    __syncthreads();
    if (ch == 0 && lq == 0) {
        #pragma unroll
        for (int p = 0; p < 16; ++p) KINSERT16(keys, thr, mbuf[(16 * rb + l15) * 16 + p])
        int* op = ci + ((size_t)b * N_ + grow) * 16;
        #pragma unroll
        for (int p = 0; p < 16; ++p) op[p] = 1023 - (int)(keys[p] & 1023u);
    }
}

// ---------------------------------------------------------------------------
// 3) rescore — REVERTED to passing r14 form (coalesced 16-lane dots + INSERT9)
// ---------------------------------------------------------------------------
__global__ __launch_bounds__(TPB) void rescore_kernel(const float* __restrict__ xnt,
                                                      const int* __restrict__ ci,
                                                      int* __restrict__ idxo) {
    const int tid = threadIdx.x;
    const int g = tid >> 4, l = tid & 15;
    const size_t row = (size_t)blockIdx.x * 16 + g;       // global row 0..32767
    const int nrow = (int)(row & (N_ - 1));               // token index within batch
    const float* xbase = xnt + (row >> 10) * (size_t)CN_; // batch base
    const float* rvp = xbase + (size_t)nrow * C_;

    float rv[8];
    #pragma unroll
    for (int t = 0; t < 8; ++t) rv[t] = rvp[t * 16 + l];

    float val[9]; int id[9];
    #pragma unroll
    for (int p = 0; p < 9; ++p) { val[p] = -1e30f; id[p] = -1; }

    const int* cp = ci + row * 16;
    #pragma unroll 4
    for (int j = 0; j < 16; ++j) {
        int cand = cp[j];
        const float* cv = xbase + (size_t)cand * C_;
        float s = 0.f;
        #pragma unroll
        for (int t = 0; t < 8; ++t) s = fmaf(rv[t], cv[t * 16 + l], s);
        #pragma unroll
        for (int d = 1; d < 16; d <<= 1) s += __shfl_xor(s, d);
        float v = (cand == nrow) ? INFV : s;
        INSERT9(val, id, v, cand)
    }
    if (l == 0) {
        int* op = idxo + row * 9;
        #pragma unroll
        for (int p = 0; p < 9; ++p) op[p] = id[p];
    }
}

// ---------------------------------------------------------------------------
// 4) MFMA conv (unchanged, passing): 128o x 128n per block
// ---------------------------------------------------------------------------
__global__ __launch_bounds__(TPB) void conv_mfma_kernel(const __hip_bfloat16* __restrict__ xtb,
                                                        const __hip_bfloat16* __restrict__ wbh,
                                                        const __hip_bfloat16* __restrict__ wbl,
                                                        const int* __restrict__ idxi,
                                                        float* __restrict__ out) {
    __shared__ __align__(16) __hip_bfloat16 gbuf[2][128 * 64];
    __shared__ __align__(16) __hip_bfloat16 hbuf[2][128 * 64];
    __shared__ __align__(16) __hip_bfloat16 lbuf[2][128 * 64];
    __shared__ int ids[K_ * 128];

    const int tid = threadIdx.x;
    const int lane = tid & 63;
    const int wv = tid >> 6;
    const int b  = blockIdx.x >> 3;
    const int n0 = (blockIdx.x & 7) << 7;
    const __hip_bfloat16* xb = xtb + (size_t)b * CN_;

    for (int j = tid; j < K_ * 128; j += TPB) {
        int k = j >> 7, r = j & 127;
        ids[j] = idxi[((size_t)b * N_ + n0 + r) * K_ + k];
    }
    __syncthreads();

    f32x4 acc[2][8];
    #pragma unroll
    for (int mt = 0; mt < 2; ++mt)
        #pragma unroll
        for (int nt = 0; nt < 8; ++nt) acc[mt][nt] = (f32x4){0.f, 0.f, 0.f, 0.f};

    const int swz = ((lane & 7) ^ (lane >> 3)) * 8;

#define CONV_STAGE(S, PB)                                                               \
    {                                                                                   \
        const int k_ = (S) >> 1, ch_ = ((S) & 1) * 64;                                  \
        _Pragma("unroll")                                                               \
        for (int q_ = 0; q_ < 4; ++q_) {                                                \
            int row_ = 32 * wv + 8 * q_ + (lane >> 3);                                  \
            int tok_ = ids[k_ * 128 + row_];                                            \
            gload_lds16(xb + (size_t)tok_ * C_ + ch_ + swz, &gbuf[PB][(32 * wv + 8 * q_) * 64]); \
            const size_t wr_ = ((size_t)k_ * 128 + row_) * C_ + ch_ + swz;              \
            gload_lds16(wbh + wr_, &hbuf[PB][(32 * wv + 8 * q_) * 64]);                 \
            gload_lds16(wbl + wr_, &lbuf[PB][(32 * wv + 8 * q_) * 64]);                 \
        }                                                                               \
    }

    CONV_STAGE(0, 0)
    __syncthreads();

    const int l15 = lane & 15, l7 = lane & 7, lq = lane >> 4;
    int pb = 0;
    #pragma unroll 1
    for (int s = 0; s < 18; ++s) {
        if (s < 17) CONV_STAGE(s + 1, pb ^ 1)
        const __hip_bfloat16* G = gbuf[pb];
        const __hip_bfloat16* H = hbuf[pb];
        const __hip_bfloat16* L = lbuf[pb];
        #pragma unroll
        for (int kc = 0; kc < 2; ++kc) {
            const int phys = ((kc * 4 + lq) ^ l7) * 8;
            s16x8 bb[8];
            #pragma unroll
            for (int nt = 0; nt < 8; ++nt)
                bb[nt] = *(const s16x8*)&G[(16 * nt + l15) * 64 + phys];
            #pragma unroll
            for (int mt = 0; mt < 2; ++mt) {
                const int orow = (32 * wv + 16 * mt + l15) * 64 + phys;
                s16x8 ah = *(const s16x8*)&H[orow];
                s16x8 al = *(const s16x8*)&L[orow];
                #pragma unroll
                for (int nt = 0; nt < 8; ++nt) {
                    acc[mt][nt] = __builtin_amdgcn_mfma_f32_16x16x32_bf16(ah, bb[nt], acc[mt][nt], 0, 0, 0);
                    acc[mt][nt] = __builtin_amdgcn_mfma_f32_16x16x32_bf16(al, bb[nt], acc[mt][nt], 0, 0, 0);
                }
            }
        }
        __syncthreads();
        pb ^= 1;
    }

    float* ob = out + (size_t)b * CN_;
    #pragma unroll
    for (int mt = 0; mt < 2; ++mt)
        #pragma unroll
        for (int nt = 0; nt < 8; ++nt) {
            int o = 32 * wv + 16 * mt + lq * 4;
            int n = n0 + 16 * nt + l15;
            #pragma unroll
            for (int r = 0; r < 4; ++r)
                ob[(size_t)(o + r) * N_ + n] = acc[mt][nt][r];
        }
#undef CONV_STAGE
}

// ---------------------------------------------------------------------------
extern "C" void kernel_launch(void* const* d_in, const int* in_sizes, int n_in,
                              void* d_out, int out_size, void* d_ws, size_t ws_size,
                              hipStream_t stream) {
    (void)in_sizes; (void)n_in; (void)out_size;
    const float* x = (const float*)d_in[0];
    const float* W = (const float*)d_in[1];
    float* out = (float*)d_out;
    float* ws  = (float*)d_ws;

    float* xnt = ws + XNT_OFF;
    __hip_bfloat16* xnb = (__hip_bfloat16*)(ws + XNB_OFF);

    if (ws_size >= FUSED_BYTES) {
        // fused path: xtb in its own region; 4 kernels total
        __hip_bfloat16* xtb = (__hip_bfloat16*)(ws + XTB_U);
        __hip_bfloat16* wbh = (__hip_bfloat16*)(ws + WBH_U);
        __hip_bfloat16* wbl = (__hip_bfloat16*)(ws + WBL_U);
        int* ci  = (int*)(ws + CI_U);
        int* idx = (int*)(ws + IDX_U);

        prep_all_kernel<<<512 + (K_ * C_ * C_) / TPB, TPB, 0, stream>>>(x, W, xnt, xnb, xtb, wbh, wbl);
        sim_mfma_topk_kernel<<<B_ * 32, TPB, 0, stream>>>(xnb, ci);
        rescore_kernel<<<(B_ * N_) / 16, TPB, 0, stream>>>(xnt, ci, idx);
        conv_mfma_kernel<<<B_ * 8, TPB, 0, stream>>>(xtb, wbh, wbl, idx, out);
    } else {
        // fallback: byte-identical r14 pipeline (29 MB layout, xtb aliases xnb)
        __hip_bfloat16* xtb = (__hip_bfloat16*)(ws + XNB_OFF);
        __hip_bfloat16* wbh = (__hip_bfloat16*)(ws + WBH_F);
        __hip_bfloat16* wbl = (__hip_bfloat16*)(ws + WBL_F);
        int* ci  = (int*)(ws + CI_F);
        int* idx = (int*)(ws + IDX_F);

        normtrans_kernel<<<B_ * 16, TPB, 0, stream>>>(x, xnt, xnb);
        wbprep_kernel<<<(K_ * C_ * C_) / TPB, TPB, 0, stream>>>(W, wbh, wbl);
        sim_mfma_topk_kernel<<<B_ * 32, TPB, 0, stream>>>(xnb, ci);
        rescore_kernel<<<(B_ * N_) / 16, TPB, 0, stream>>>(xnt, ci, idx);
        transpose_bf16_kernel<<<B_ * 16, TPB, 0, stream>>>(x, xtb);  // xnb dead now
        conv_mfma_kernel<<<B_ * 8, TPB, 0, stream>>>(xtb, wbh, wbl, idx, out);
    }
}